// Round 1
// baseline (365.958 us; speedup 1.0000x reference)
//
#include <hip/hip_runtime.h>

#define H 128
#define RREL 8
#define NJ 9        // 8 relations + root
#define MT 32       // dsts per layer-block
#define LROW 1160   // agg LDS row stride in elems (1152 + 8 pad; 2320B = 145*16B, ≡4 dw mod 32)

typedef short bf16x8 __attribute__((ext_vector_type(8)));
typedef float f32x4 __attribute__((ext_vector_type(4)));
typedef unsigned short u16x8 __attribute__((ext_vector_type(8)));

static __device__ __forceinline__ unsigned short f2bf(float f) {
    unsigned int u = __float_as_uint(f);
    unsigned int r = (u + 0x7fffu + ((u >> 16) & 1u)) >> 16;
    return (unsigned short)r;
}
static __device__ __forceinline__ float bf2f(unsigned short u) {
    return __uint_as_float(((unsigned int)u) << 16);
}

__global__ void zero_kernel(int* p, long n) {
    long i = (long)blockIdx.x * blockDim.x + threadIdx.x;
    long stride = (long)gridDim.x * blockDim.x;
    for (; i < n; i += stride) p[i] = 0;
}

__global__ void count_kernel(const int* __restrict__ ei, const int* __restrict__ et,
                             int* __restrict__ cnt, int E) {
    int e = blockIdx.x * 256 + threadIdx.x;
    if (e >= E) return;
    int d = ei[E + e];
    int r = et[e];
    atomicAdd(&cnt[(size_t)d * RREL + r], 1);
}

__global__ void scan_block_kernel(const int* __restrict__ cnt, int* __restrict__ rploc,
                                  int* __restrict__ bsum, int N) {
    __shared__ int s[256];
    int t = threadIdx.x;
    int d = blockIdx.x * 256 + t;
    int v = 0;
    if (d < N) {
#pragma unroll
        for (int r = 0; r < RREL; ++r) v += cnt[(size_t)d * RREL + r];
    }
    s[t] = v;
    __syncthreads();
#pragma unroll
    for (int off = 1; off < 256; off <<= 1) {
        int u = 0;
        if (t >= off) u = s[t - off];
        __syncthreads();
        s[t] += u;
        __syncthreads();
    }
    if (d < N) rploc[d] = s[t] - v;
    if (t == 255) bsum[blockIdx.x] = s[255];
}

__global__ void scan_top_kernel(const int* __restrict__ bsum, int* __restrict__ boff, int nb) {
    __shared__ int s[256];
    int t = threadIdx.x;
    int v = (t < nb) ? bsum[t] : 0;
    s[t] = v;
    __syncthreads();
#pragma unroll
    for (int off = 1; off < 256; off <<= 1) {
        int u = 0;
        if (t >= off) u = s[t - off];
        __syncthreads();
        s[t] += u;
        __syncthreads();
    }
    boff[t] = s[t] - v;
}

// rowptr[d] = dst-bin start; rowptr2[d*8+r] = (dst,rel)-subbin start; inv = 1/max(cnt,1)
__global__ void finalize_kernel(const int* __restrict__ cnt, const int* __restrict__ rploc,
                                const int* __restrict__ boff, int* __restrict__ rowptr,
                                int* __restrict__ rowptr2, float* __restrict__ inv, int N) {
    int d = blockIdx.x * 256 + threadIdx.x;
    if (d >= N) return;
    int rp = rploc[d] + boff[d >> 8];
    rowptr[d] = rp;
    int run = rp;
#pragma unroll
    for (int r = 0; r < RREL; ++r) {
        int c = cnt[(size_t)d * RREL + r];
        rowptr2[(size_t)d * RREL + r] = run;
        inv[(size_t)d * RREL + r] = 1.0f / (float)max(c, 1);
        run += c;
    }
    if (d == N - 1) rowptr[N] = run;
}

// packed[pos] = src | (rel<<20), binned by (dst, rel) -> rel-sorted within each dst bin
__global__ void fill_kernel(const int* __restrict__ ei, const int* __restrict__ et,
                            int* __restrict__ cursor, const int* __restrict__ rowptr2,
                            int* __restrict__ packed, int E) {
    int e = blockIdx.x * 256 + threadIdx.x;
    if (e >= E) return;
    int d = ei[E + e];
    int r = et[e];
    size_t bin = (size_t)d * RREL + r;
    int pos = rowptr2[bin] + atomicAdd(&cursor[bin], 1);
    packed[pos] = ei[e] | (r << 20);
}

__global__ void tobf_kernel(const float* __restrict__ x, unsigned short* __restrict__ xb, long n) {
    long i = (long)blockIdx.x * blockDim.x + threadIdx.x;
    long stride = (long)gridDim.x * blockDim.x;
    for (; i < n; i += stride) xb[i] = f2bf(x[i]);
}

// WTa[j][f][k] = W[j][k][f] (j<8) or root[k][f] (j==8); bias natural order.
__global__ void wcat_kernel(const float* __restrict__ W1, const float* __restrict__ r1,
                            const float* __restrict__ W2, const float* __restrict__ r2,
                            const float* __restrict__ b1, const float* __restrict__ b2,
                            unsigned short* __restrict__ WTa1, unsigned short* __restrict__ WTa2,
                            float* __restrict__ biasP) {
    int id = blockIdx.x * 256 + threadIdx.x;
    const int per = NJ * H * H;
    if (id < per) {
        int j = id / (H * H);
        int fk = id - j * (H * H);
        int f = fk >> 7, k = fk & 127;
        float v1 = (j < RREL) ? W1[((size_t)j * H + k) * H + f] : r1[(size_t)k * H + f];
        WTa1[id] = f2bf(v1);
        float v2 = (j < RREL) ? W2[((size_t)j * H + k) * H + f] : r2[(size_t)k * H + f];
        WTa2[id] = f2bf(v2);
    } else if (id < per + 2 * H) {
        int c = id - per;
        biasP[c] = (c < H) ? b1[c] : b2[c - H];
    }
}

// Fused RGCN layer: aggregate-then-transform.
// Phase 1: per dst (one 16-lane group), accumulate agg[r][:] = sum inv*x[src] in fp32 regs
//          (edges rel-sorted -> one bf16 LDS write per (d,r) slot); agg[8] = x[d] (root).
// Phase 2: out[32x128] = agg[32x1152] @ Wcat[1152x128] via MFMA, W streamed from L2.
// Epilogue: +bias, relu?, coalesced store via LDS fp32 staging.
__global__ __launch_bounds__(512) void layer_kernel(const unsigned short* __restrict__ xin,
                                                    const unsigned short* __restrict__ WTa,
                                                    const float* __restrict__ biasP,
                                                    const float* __restrict__ inv,
                                                    const int* __restrict__ rowptr,
                                                    const int* __restrict__ packed,
                                                    float* __restrict__ outf,
                                                    unsigned short* __restrict__ outb,
                                                    int N, int relu) {
    __shared__ __align__(16) unsigned short aggS[MT * LROW];
    const int t = threadIdx.x;
    const int l = t & 63;
    const int w = t >> 6;           // wave 0..7
    const int g16 = t >> 4;         // group (dst) 0..31
    const int fl = t & 15;
    const int gbase = l & 48;
    const int Mbase = blockIdx.x * MT;
    const int d = Mbase + g16;
    const bool valid = d < N;

    unsigned short* rowp = &aggS[g16 * LROW];
    {
        u16x8 z = {0, 0, 0, 0, 0, 0, 0, 0};
#pragma unroll
        for (int c = 0; c < 8; ++c) *(u16x8*)&rowp[(c * 16 + fl) * 8] = z;  // zero rel slots
        if (valid) {  // root slot j=8: x[d] itself (coefficient 1)
            *(u16x8*)&rowp[RREL * H + fl * 8] = *(const u16x8*)&xin[(size_t)d * H + fl * 8];
        } else {
            *(u16x8*)&rowp[RREL * H + fl * 8] = z;
        }
    }

    int rp = 0;
    if (valid && fl < 2) rp = rowptr[d + fl];
    float ivl = 0.f;
    if (valid && fl < 8) ivl = inv[(size_t)d * RREL + fl];
    int beg = __shfl(rp, gbase);
    int end = __shfl(rp, gbase + 1);

    float tmp[8] = {};
    float ivc = 0.f;
    int rcur = -1;
    for (int i = beg; i < end; i += 16) {
        int pk = (i + fl < end) ? packed[i + fl] : 0;
        int m = end - i;
        if (m > 16) m = 16;
        for (int e = 0; e < m; ++e) {
            int v = __shfl(pk, gbase + e);
            int s = v & 0xFFFFF, r = v >> 20;
            if (r != rcur) {  // rel boundary: flush previous subbin (exactly once per (d,r))
                if (rcur >= 0) {
                    u16x8 o;
#pragma unroll
                    for (int j = 0; j < 8; ++j) o[j] = f2bf(ivc * tmp[j]);
                    *(u16x8*)&rowp[rcur * H + fl * 8] = o;
                }
                rcur = r;
                ivc = __shfl(ivl, gbase + r);
#pragma unroll
                for (int j = 0; j < 8; ++j) tmp[j] = 0.f;
            }
            u16x8 xv = *(const u16x8*)&xin[(size_t)s * H + fl * 8];
#pragma unroll
            for (int j = 0; j < 8; ++j) tmp[j] += bf2f((unsigned short)xv[j]);
        }
    }
    if (rcur >= 0) {
        u16x8 o;
#pragma unroll
        for (int j = 0; j < 8; ++j) o[j] = f2bf(ivc * tmp[j]);
        *(u16x8*)&rowp[rcur * H + fl * 8] = o;
    }

    __syncthreads();

    // Phase 2: wave w owns output cols [w*16, w*16+16), both 16-row halves.
    const int colb = l & 15, quad = l >> 4;
    const int fcol = w * 16 + colb;
    const f32x4 fz = {0.f, 0.f, 0.f, 0.f};
    f32x4 acc0 = fz, acc1 = fz;
    const unsigned short* arow0 = &aggS[colb * LROW];
    const unsigned short* arow1 = &aggS[(16 + colb) * LROW];
#pragma unroll
    for (int j = 0; j < NJ; ++j) {
#pragma unroll
        for (int ks = 0; ks < 4; ++ks) {
            const int kl = ks * 32 + quad * 8;
            bf16x8 b = *(const bf16x8*)&WTa[((size_t)j * H + fcol) * H + kl];
            bf16x8 a0 = *(const bf16x8*)&arow0[j * H + kl];
            bf16x8 a1 = *(const bf16x8*)&arow1[j * H + kl];
            acc0 = __builtin_amdgcn_mfma_f32_16x16x32_bf16(a0, b, acc0, 0, 0, 0);
            acc1 = __builtin_amdgcn_mfma_f32_16x16x32_bf16(a1, b, acc1, 0, 0, 0);
        }
    }

    __syncthreads();  // all aggS reads done; reuse as fp32 staging [32][132]
    float* stg = (float*)aggS;
    const float bcol = biasP[fcol];
#pragma unroll
    for (int i = 0; i < 4; ++i) {
        float v0 = acc0[i] + bcol;
        float v1 = acc1[i] + bcol;
        if (relu) { v0 = fmaxf(v0, 0.f); v1 = fmaxf(v1, 0.f); }
        stg[(quad * 4 + i) * 132 + fcol] = v0;
        stg[(16 + quad * 4 + i) * 132 + fcol] = v1;
    }
    __syncthreads();
    {
        int row = t >> 4;           // 0..31
        int dd = Mbase + row;
        if (dd < N) {
            int c0 = fl * 8;
            f32x4 p0 = *(const f32x4*)&stg[row * 132 + c0];
            f32x4 p1 = *(const f32x4*)&stg[row * 132 + c0 + 4];
            if (outf) {
                *(f32x4*)&outf[(size_t)dd * H + c0] = p0;
                *(f32x4*)&outf[(size_t)dd * H + c0 + 4] = p1;
            } else {
                u16x8 o;
#pragma unroll
                for (int j = 0; j < 4; ++j) { o[j] = f2bf(p0[j]); o[4 + j] = f2bf(p1[j]); }
                *(u16x8*)&outb[(size_t)dd * H + c0] = o;
            }
        }
    }
}

extern "C" void kernel_launch(void* const* d_in, const int* in_sizes, int n_in,
                              void* d_out, int out_size, void* d_ws, size_t ws_size,
                              hipStream_t stream) {
    const int* edge_index = (const int*)d_in[0];
    const int* edge_type  = (const int*)d_in[1];
    const float* node_emb = (const float*)d_in[2];
    const float* W1    = (const float*)d_in[3];
    const float* root1 = (const float*)d_in[4];
    const float* b1    = (const float*)d_in[5];
    const float* W2    = (const float*)d_in[6];
    const float* root2 = (const float*)d_in[7];
    const float* b2    = (const float*)d_in[8];
    float* out = (float*)d_out;

    const int E = in_sizes[1];
    const int N = in_sizes[2] / H;

    char* base = (char*)d_ws;
    size_t off = 0;
    auto take = [&](size_t bytes) { size_t o = off; off = (off + bytes + 63) & ~(size_t)63; return o; };
    int*   cnt     = (int*)  (base + take((size_t)N * RREL * 4));
    int*   cursor8 = (int*)  (base + take((size_t)N * RREL * 4));  // adjacent to cnt: single zero pass
    int*   rploc   = (int*)  (base + take((size_t)N * 4));
    int*   bsum    = (int*)  (base + take(256 * 4));
    int*   boff    = (int*)  (base + take(256 * 4));
    int*   rowptr  = (int*)  (base + take(((size_t)N + 1) * 4));
    int*   rowptr2 = (int*)  (base + take((size_t)N * RREL * 4));
    float* inv     = (float*)(base + take((size_t)N * RREL * 4));
    int*   packed  = (int*)  (base + take((size_t)E * 4));
    unsigned short* WTa1 = (unsigned short*)(base + take((size_t)NJ * H * H * 2));
    unsigned short* WTa2 = (unsigned short*)(base + take((size_t)NJ * H * H * 2));
    float* biasP   = (float*)(base + take(2 * H * 4));
    unsigned short* xb  = (unsigned short*)(base + take((size_t)N * H * 2));
    unsigned short* hb  = (unsigned short*)(base + take((size_t)N * H * 2));
    (void)ws_size;

    const int nbScan = (N + 255) / 256;

    zero_kernel<<<512, 256, 0, stream>>>(cnt, (long)N * (2 * RREL));  // cnt + cursor8
    count_kernel<<<(E + 255) / 256, 256, 0, stream>>>(edge_index, edge_type, cnt, E);
    scan_block_kernel<<<nbScan, 256, 0, stream>>>(cnt, rploc, bsum, N);
    scan_top_kernel<<<1, 256, 0, stream>>>(bsum, boff, nbScan);
    finalize_kernel<<<nbScan, 256, 0, stream>>>(cnt, rploc, boff, rowptr, rowptr2, inv, N);
    fill_kernel<<<(E + 255) / 256, 256, 0, stream>>>(edge_index, edge_type, cursor8, rowptr2, packed, E);
    wcat_kernel<<<(NJ * H * H + 2 * H + 255) / 256, 256, 0, stream>>>(W1, root1, W2, root2, b1, b2,
                                                                      WTa1, WTa2, biasP);
    tobf_kernel<<<1024, 256, 0, stream>>>(node_emb, xb, (long)N * H);

    const int gl = (N + MT - 1) / MT;
    layer_kernel<<<gl, 512, 0, stream>>>(xb, WTa1, biasP, inv, rowptr, packed,
                                         nullptr, hb, N, 1);
    layer_kernel<<<gl, 512, 0, stream>>>(hb, WTa2, biasP + H, inv, rowptr, packed,
                                         out, nullptr, N, 0);
}

// Round 2
// 339.983 us; speedup vs baseline: 1.0764x; 1.0764x over previous
//
#include <hip/hip_runtime.h>

#define H 128
#define RREL 8
#define NJ 9        // 8 relations + root
#define MT 32       // dsts per layer-block
#define LROW 1160   // agg LDS row stride in elems (1152 + 8 pad; 2320B = 145*16B)

typedef short bf16x8 __attribute__((ext_vector_type(8)));
typedef float f32x4 __attribute__((ext_vector_type(4)));
typedef unsigned short u16x8 __attribute__((ext_vector_type(8)));

static __device__ __forceinline__ unsigned short f2bf(float f) {
    unsigned int u = __float_as_uint(f);
    unsigned int r = (u + 0x7fffu + ((u >> 16) & 1u)) >> 16;
    return (unsigned short)r;
}
static __device__ __forceinline__ float bf2f(unsigned short u) {
    return __uint_as_float(((unsigned int)u) << 16);
}

__global__ void zero_kernel(int* p, long n) {
    long i = (long)blockIdx.x * blockDim.x + threadIdx.x;
    long stride = (long)gridDim.x * blockDim.x;
    for (; i < n; i += stride) p[i] = 0;
}

__global__ void count_kernel(const int* __restrict__ ei, const int* __restrict__ et,
                             int* __restrict__ cnt, int E) {
    int e = blockIdx.x * 256 + threadIdx.x;
    if (e >= E) return;
    int d = ei[E + e];
    int r = et[e];
    atomicAdd(&cnt[(size_t)d * RREL + r], 1);
}

__global__ void scan_block_kernel(const int* __restrict__ cnt, int* __restrict__ rploc,
                                  int* __restrict__ bsum, int N) {
    __shared__ int s[256];
    int t = threadIdx.x;
    int d = blockIdx.x * 256 + t;
    int v = 0;
    if (d < N) {
#pragma unroll
        for (int r = 0; r < RREL; ++r) v += cnt[(size_t)d * RREL + r];
    }
    s[t] = v;
    __syncthreads();
#pragma unroll
    for (int off = 1; off < 256; off <<= 1) {
        int u = 0;
        if (t >= off) u = s[t - off];
        __syncthreads();
        s[t] += u;
        __syncthreads();
    }
    if (d < N) rploc[d] = s[t] - v;
    if (t == 255) bsum[blockIdx.x] = s[255];
}

__global__ void scan_top_kernel(const int* __restrict__ bsum, int* __restrict__ boff, int nb) {
    __shared__ int s[256];
    int t = threadIdx.x;
    int v = (t < nb) ? bsum[t] : 0;
    s[t] = v;
    __syncthreads();
#pragma unroll
    for (int off = 1; off < 256; off <<= 1) {
        int u = 0;
        if (t >= off) u = s[t - off];
        __syncthreads();
        s[t] += u;
        __syncthreads();
    }
    boff[t] = s[t] - v;
}

// rowptr[d] = dst-bin start; rowptr2[d*8+r] = (dst,rel)-subbin start; inv = 1/max(cnt,1)
__global__ void finalize_kernel(const int* __restrict__ cnt, const int* __restrict__ rploc,
                                const int* __restrict__ boff, int* __restrict__ rowptr,
                                int* __restrict__ rowptr2, float* __restrict__ inv, int N) {
    int d = blockIdx.x * 256 + threadIdx.x;
    if (d >= N) return;
    int rp = rploc[d] + boff[d >> 8];
    rowptr[d] = rp;
    int run = rp;
#pragma unroll
    for (int r = 0; r < RREL; ++r) {
        int c = cnt[(size_t)d * RREL + r];
        rowptr2[(size_t)d * RREL + r] = run;
        inv[(size_t)d * RREL + r] = 1.0f / (float)max(c, 1);
        run += c;
    }
    if (d == N - 1) rowptr[N] = run;
}

// packed[pos] = src | (rel<<20), binned by (dst, rel) -> rel-sorted within each dst bin
__global__ void fill_kernel(const int* __restrict__ ei, const int* __restrict__ et,
                            int* __restrict__ cursor, const int* __restrict__ rowptr2,
                            int* __restrict__ packed, int E) {
    int e = blockIdx.x * 256 + threadIdx.x;
    if (e >= E) return;
    int d = ei[E + e];
    int r = et[e];
    size_t bin = (size_t)d * RREL + r;
    int pos = rowptr2[bin] + atomicAdd(&cursor[bin], 1);
    packed[pos] = ei[e] | (r << 20);
}

__global__ void tobf_kernel(const float* __restrict__ x, unsigned short* __restrict__ xb, long n) {
    long i = (long)blockIdx.x * blockDim.x + threadIdx.x;
    long stride = (long)gridDim.x * blockDim.x;
    for (; i < n; i += stride) xb[i] = f2bf(x[i]);
}

// WTa[j][f][k] = W[j][k][f] (j<8) or root[k][f] (j==8); bias natural order.
__global__ void wcat_kernel(const float* __restrict__ W1, const float* __restrict__ r1,
                            const float* __restrict__ W2, const float* __restrict__ r2,
                            const float* __restrict__ b1, const float* __restrict__ b2,
                            unsigned short* __restrict__ WTa1, unsigned short* __restrict__ WTa2,
                            float* __restrict__ biasP) {
    int id = blockIdx.x * 256 + threadIdx.x;
    const int per = NJ * H * H;
    if (id < per) {
        int j = id / (H * H);
        int fk = id - j * (H * H);
        int f = fk >> 7, k = fk & 127;
        float v1 = (j < RREL) ? W1[((size_t)j * H + k) * H + f] : r1[(size_t)k * H + f];
        WTa1[id] = f2bf(v1);
        float v2 = (j < RREL) ? W2[((size_t)j * H + k) * H + f] : r2[(size_t)k * H + f];
        WTa2[id] = f2bf(v2);
    } else if (id < per + 2 * H) {
        int c = id - per;
        biasP[c] = (c < H) ? b1[c] : b2[c - H];
    }
}

// Fused RGCN layer: aggregate-then-transform.
// Phase 1: per dst (one 16-lane group), branchless rel-sorted edge walk:
//   - 8-deep load batching (8 independent x[src] loads in flight per step)
//   - predicated reset on rel boundary (no branch), predicated add for e>=m
//     (clamped dup of bin's last edge: same r, adds 0 -> harmless)
//   - flush EVERY edge: rowp[r] = f2bf(iv*tmp); rel-sorted => last write per
//     (d,r) slot is the complete sum. Zero divergent branches in the body.
// Phase 2: out[32x128] = agg[32x1152] @ Wcat[1152x128] via MFMA, W streamed from L2.
// Epilogue: +bias, relu?, coalesced store via LDS fp32 staging.
__global__ __launch_bounds__(512) void layer_kernel(const unsigned short* __restrict__ xin,
                                                    const unsigned short* __restrict__ WTa,
                                                    const float* __restrict__ biasP,
                                                    const float* __restrict__ inv,
                                                    const int* __restrict__ rowptr,
                                                    const int* __restrict__ packed,
                                                    float* __restrict__ outf,
                                                    unsigned short* __restrict__ outb,
                                                    int N, int relu) {
    __shared__ __align__(16) unsigned short aggS[MT * LROW];
    const int t = threadIdx.x;
    const int l = t & 63;
    const int w = t >> 6;           // wave 0..7
    const int g16 = t >> 4;         // group (dst) 0..31
    const int fl = t & 15;
    const int gbase = l & 48;
    const int Mbase = blockIdx.x * MT;
    const int d = Mbase + g16;
    const bool valid = d < N;

    unsigned short* rowp = &aggS[g16 * LROW];
    {
        u16x8 z = {0, 0, 0, 0, 0, 0, 0, 0};
#pragma unroll
        for (int c = 0; c < 8; ++c) *(u16x8*)&rowp[(c * 16 + fl) * 8] = z;  // zero rel slots
        if (valid) {  // root slot j=8: x[d] itself (coefficient 1)
            *(u16x8*)&rowp[RREL * H + fl * 8] = *(const u16x8*)&xin[(size_t)d * H + fl * 8];
        } else {
            *(u16x8*)&rowp[RREL * H + fl * 8] = z;
        }
    }

    int rp = 0;
    if (valid && fl < 2) rp = rowptr[d + fl];
    float ivl = 0.f;
    if (valid && fl < 8) ivl = inv[(size_t)d * RREL + fl];
    int beg = __shfl(rp, gbase);
    int end = __shfl(rp, gbase + 1);

    float tmp[8] = {};
    int rcur = RREL;  // sentinel: first real edge always resets
    for (int i = beg; i < end; i += 16) {
        int idx = i + fl;
        if (idx > end - 1) idx = end - 1;  // clamp: dup of bin's last edge
        int pk = packed[idx];
        int m = end - i;
        if (m > 16) m = 16;
#pragma unroll
        for (int half = 0; half < 2; ++half) {
            u16x8 xv[8];
#pragma unroll
            for (int e = 0; e < 8; ++e) {  // batch: 8 loads in flight
                int v = __shfl(pk, gbase + half * 8 + e);
                int s = v & 0xFFFFF;
                xv[e] = *(const u16x8*)&xin[(size_t)s * H + fl * 8];
            }
#pragma unroll
            for (int e = 0; e < 8; ++e) {
                int ee = half * 8 + e;
                int v = __shfl(pk, gbase + ee);
                int r = v >> 20;
                float ivc = __shfl(ivl, gbase + r);
                bool pred = ee < m;
                bool nr = (r != rcur);
                u16x8 o;
#pragma unroll
                for (int j = 0; j < 8; ++j) {
                    float x = bf2f((unsigned short)xv[e][j]);
                    float t0 = nr ? 0.f : tmp[j];
                    tmp[j] = t0 + (pred ? x : 0.f);
                    o[j] = f2bf(ivc * tmp[j]);
                }
                *(u16x8*)&rowp[r * H + fl * 8] = o;
                rcur = r;
            }
        }
    }

    __syncthreads();

    // Phase 2: wave w owns output cols [w*16, w*16+16), both 16-row halves.
    const int colb = l & 15, quad = l >> 4;
    const int fcol = w * 16 + colb;
    const f32x4 fz = {0.f, 0.f, 0.f, 0.f};
    f32x4 acc0 = fz, acc1 = fz;
    const unsigned short* arow0 = &aggS[colb * LROW];
    const unsigned short* arow1 = &aggS[(16 + colb) * LROW];
#pragma unroll
    for (int j = 0; j < NJ; ++j) {
#pragma unroll
        for (int ks = 0; ks < 4; ++ks) {
            const int kl = ks * 32 + quad * 8;
            bf16x8 b = *(const bf16x8*)&WTa[((size_t)j * H + fcol) * H + kl];
            bf16x8 a0 = *(const bf16x8*)&arow0[j * H + kl];
            bf16x8 a1 = *(const bf16x8*)&arow1[j * H + kl];
            acc0 = __builtin_amdgcn_mfma_f32_16x16x32_bf16(a0, b, acc0, 0, 0, 0);
            acc1 = __builtin_amdgcn_mfma_f32_16x16x32_bf16(a1, b, acc1, 0, 0, 0);
        }
    }

    __syncthreads();  // all aggS reads done; reuse as fp32 staging [32][132]
    float* stg = (float*)aggS;
    const float bcol = biasP[fcol];
#pragma unroll
    for (int i = 0; i < 4; ++i) {
        float v0 = acc0[i] + bcol;
        float v1 = acc1[i] + bcol;
        if (relu) { v0 = fmaxf(v0, 0.f); v1 = fmaxf(v1, 0.f); }
        stg[(quad * 4 + i) * 132 + fcol] = v0;
        stg[(16 + quad * 4 + i) * 132 + fcol] = v1;
    }
    __syncthreads();
    {
        int row = t >> 4;           // 0..31
        int dd = Mbase + row;
        if (dd < N) {
            int c0 = fl * 8;
            f32x4 p0 = *(const f32x4*)&stg[row * 132 + c0];
            f32x4 p1 = *(const f32x4*)&stg[row * 132 + c0 + 4];
            if (outf) {
                *(f32x4*)&outf[(size_t)dd * H + c0] = p0;
                *(f32x4*)&outf[(size_t)dd * H + c0 + 4] = p1;
            } else {
                u16x8 o;
#pragma unroll
                for (int j = 0; j < 4; ++j) { o[j] = f2bf(p0[j]); o[4 + j] = f2bf(p1[j]); }
                *(u16x8*)&outb[(size_t)dd * H + c0] = o;
            }
        }
    }
}

extern "C" void kernel_launch(void* const* d_in, const int* in_sizes, int n_in,
                              void* d_out, int out_size, void* d_ws, size_t ws_size,
                              hipStream_t stream) {
    const int* edge_index = (const int*)d_in[0];
    const int* edge_type  = (const int*)d_in[1];
    const float* node_emb = (const float*)d_in[2];
    const float* W1    = (const float*)d_in[3];
    const float* root1 = (const float*)d_in[4];
    const float* b1    = (const float*)d_in[5];
    const float* W2    = (const float*)d_in[6];
    const float* root2 = (const float*)d_in[7];
    const float* b2    = (const float*)d_in[8];
    float* out = (float*)d_out;

    const int E = in_sizes[1];
    const int N = in_sizes[2] / H;

    char* base = (char*)d_ws;
    size_t off = 0;
    auto take = [&](size_t bytes) { size_t o = off; off = (off + bytes + 63) & ~(size_t)63; return o; };
    int*   cnt     = (int*)  (base + take((size_t)N * RREL * 4));
    int*   cursor8 = (int*)  (base + take((size_t)N * RREL * 4));  // adjacent to cnt: single zero pass
    int*   rploc   = (int*)  (base + take((size_t)N * 4));
    int*   bsum    = (int*)  (base + take(256 * 4));
    int*   boff    = (int*)  (base + take(256 * 4));
    int*   rowptr  = (int*)  (base + take(((size_t)N + 1) * 4));
    int*   rowptr2 = (int*)  (base + take((size_t)N * RREL * 4));
    float* inv     = (float*)(base + take((size_t)N * RREL * 4));
    int*   packed  = (int*)  (base + take((size_t)E * 4));
    unsigned short* WTa1 = (unsigned short*)(base + take((size_t)NJ * H * H * 2));
    unsigned short* WTa2 = (unsigned short*)(base + take((size_t)NJ * H * H * 2));
    float* biasP   = (float*)(base + take(2 * H * 4));
    unsigned short* xb  = (unsigned short*)(base + take((size_t)N * H * 2));
    unsigned short* hb  = (unsigned short*)(base + take((size_t)N * H * 2));
    (void)ws_size;

    const int nbScan = (N + 255) / 256;

    zero_kernel<<<512, 256, 0, stream>>>(cnt, (long)N * (2 * RREL));  // cnt + cursor8
    count_kernel<<<(E + 255) / 256, 256, 0, stream>>>(edge_index, edge_type, cnt, E);
    scan_block_kernel<<<nbScan, 256, 0, stream>>>(cnt, rploc, bsum, N);
    scan_top_kernel<<<1, 256, 0, stream>>>(bsum, boff, nbScan);
    finalize_kernel<<<nbScan, 256, 0, stream>>>(cnt, rploc, boff, rowptr, rowptr2, inv, N);
    fill_kernel<<<(E + 255) / 256, 256, 0, stream>>>(edge_index, edge_type, cursor8, rowptr2, packed, E);
    wcat_kernel<<<(NJ * H * H + 2 * H + 255) / 256, 256, 0, stream>>>(W1, root1, W2, root2, b1, b2,
                                                                      WTa1, WTa2, biasP);
    tobf_kernel<<<1024, 256, 0, stream>>>(node_emb, xb, (long)N * H);

    const int gl = (N + MT - 1) / MT;
    layer_kernel<<<gl, 512, 0, stream>>>(xb, WTa1, biasP, inv, rowptr, packed,
                                         nullptr, hb, N, 1);
    layer_kernel<<<gl, 512, 0, stream>>>(hb, WTa2, biasP + H, inv, rowptr, packed,
                                         out, nullptr, N, 0);
}